// Round 9
// baseline (318.069 us; speedup 1.0000x reference)
//
#include <hip/hip_runtime.h>
#include <hip/hip_bf16.h>

// AngularMarginLoss: B=2048, D=256, C=100000
// loss = -mean_b( num_b - log(exp(num_b) + sum_{c!=t_b} exp(30*cos_bc) + 1e-6) )
// num_b = 30*cos(acos(clip(cos_bt)) + 0.2)
//
// Round-9: LDS-free, barrier-free k_main, 32 cols/wave (3128 1-wave blocks,
// ~164 regs -> 3 waves/SIMD). Single-pass W prologue: load fp32 once,
// accumulate ||row||^2 in flight, afrag holds UNNORMALIZED bf16; the
// normalization folds into the epilogue as exp(acc * srn[class]) where
// srn = 30/||w_c|| (redistributed via shfl) -- same epilogue VALU count.
// Row-sum partials via fp32 atomicAdd into 64 global banks (ws 14 -> 1.6 MB;
// the harness re-poisons d_ws every launch at ~0.72 us/MB).

static constexpr int Bn = 2048;
static constexpr int Dn = 256;
static constexpr int Cn = 100000;
static constexpr int NSLICE = 3128;                 // 32-col wave slices
static constexpr int CPAD   = NSLICE * 32;          // 100096
static constexpr float OOB_COLS = (float)(CPAD - Cn);   // 96
static constexpr int NT = Bn / 16;                  // 128 sample tiles
static constexpr int NBANK = 64;

#define SCALE_F 30.0f
#define MARGIN_F 0.2f
#define EPS_F 1e-6f

typedef __attribute__((ext_vector_type(8))) short bf16x8;   // 8 bf16 = 4 VGPRs
typedef __attribute__((ext_vector_type(4))) float f32x4;

__device__ __forceinline__ short f2bf_rne(float x) {
    union { float f; unsigned int u; } v; v.f = x;
    unsigned int r = v.u + 0x7fffu + ((v.u >> 16) & 1u);
    return (short)(r >> 16);
}

// ---- kernel 1: fused prep ----
// blocks [0,256)   : pack emb fp32 -> embF (bf16, MFMA B-fragment order)
//   chunk (t,ks,lane): embF[((t*8+ks)*64+lane)*8 + j] = bf16 of
//   emb[t*16 + (lane&15)][ks*32 + (lane>>4)*8 + j], j=0..7
// blocks [256,768) : per-sample target cosine -> numv, etv
__global__ __launch_bounds__(256) void k_prep(const float* __restrict__ W,
                                              const float* __restrict__ emb,
                                              const int* __restrict__ tgt,
                                              short* __restrict__ embF,
                                              float* __restrict__ numv,
                                              float* __restrict__ etv) {
    const int blk = blockIdx.x;
    if (blk < 256) {
        const int t     = blk >> 1;
        const int chunk = (blk & 1) * 256 + threadIdx.x;   // [0,512)
        const int ks    = chunk >> 6;
        const int lane  = chunk & 63;
        const int q     = lane >> 4;
        const int cr    = lane & 15;
        const float* src = emb + (size_t)(t * 16 + cr) * Dn + ks * 32 + q * 8;
        float4 x0 = *(const float4*)(src);
        float4 x1 = *(const float4*)(src + 4);
        bf16x8 o;
        o[0] = f2bf_rne(x0.x); o[1] = f2bf_rne(x0.y);
        o[2] = f2bf_rne(x0.z); o[3] = f2bf_rne(x0.w);
        o[4] = f2bf_rne(x1.x); o[5] = f2bf_rne(x1.y);
        o[6] = f2bf_rne(x1.z); o[7] = f2bf_rne(x1.w);
        *(bf16x8*)(embF + (size_t)((t * 8 + ks) * 64 + lane) * 8) = o;
    } else {
        const int b    = (blk - 256) * 4 + (threadIdx.x >> 6);
        const int lane = threadIdx.x & 63;
        const int t    = tgt[b];
        float4 x = *(const float4*)(W + (size_t)t * Dn + lane * 4);
        float4 e = *(const float4*)(emb + b * Dn + lane * 4);
        float dot = x.x * e.x + x.y * e.y + x.z * e.z + x.w * e.w;
        float ss  = x.x * x.x + x.y * x.y + x.z * x.z + x.w * x.w;
#pragma unroll
        for (int o = 1; o < 64; o <<= 1) {
            dot += __shfl_xor(dot, o);
            ss  += __shfl_xor(ss, o);
        }
        if (lane == 0) {
            float cosv = dot / fmaxf(sqrtf(ss), 1e-12f);
            cosv = fminf(fmaxf(cosv, -1.f), 1.f);
            const float num = SCALE_F * cosf(acosf(cosv) + MARGIN_F);
            numv[b] = num;
            etv[b]  = __expf(SCALE_F * cosv);
        }
    }
}

// ---- kernel 2: main fused GEMM + exp row-sum (1 wave/block, no LDS) ----
__global__ __launch_bounds__(64, 3) void k_main(const float* __restrict__ W,
                                                const short* __restrict__ embF,
                                                float* __restrict__ banks) {
    const int lane = threadIdx.x;
    const int q    = lane >> 4;   // quad 0..3
    const int cr   = lane & 15;
    const int sl   = blockIdx.x;
    const int cbase = sl * 32;

    // ---- prologue: single-pass load, fp32 norm in flight, bf16 unnormalized ----
    // A layout (16x16x32): lane holds A[m=cr][k=q*8+j] per 32-wide k-step.
    bf16x8 afrag[2][8];
    float  srn[2][4];     // 30/||w_c|| for epilogue classes ct*16 + q*4 + r
#pragma unroll
    for (int ct = 0; ct < 2; ++ct) {
        const int c = cbase + ct * 16 + cr;
        const float* wr = W + (size_t)c * Dn;
        float ss = 0.0f;
        if (c < Cn) {
#pragma unroll
            for (int ks = 0; ks < 8; ++ks) {
                float4 x0 = *(const float4*)(wr + ks * 32 + q * 8);
                float4 x1 = *(const float4*)(wr + ks * 32 + q * 8 + 4);
                ss += x0.x * x0.x + x0.y * x0.y + x0.z * x0.z + x0.w * x0.w;
                ss += x1.x * x1.x + x1.y * x1.y + x1.z * x1.z + x1.w * x1.w;
                bf16x8 a;
                a[0] = f2bf_rne(x0.x); a[1] = f2bf_rne(x0.y);
                a[2] = f2bf_rne(x0.z); a[3] = f2bf_rne(x0.w);
                a[4] = f2bf_rne(x1.x); a[5] = f2bf_rne(x1.y);
                a[6] = f2bf_rne(x1.z); a[7] = f2bf_rne(x1.w);
                afrag[ct][ks] = a;
            }
        } else {
#pragma unroll
            for (int ks = 0; ks < 8; ++ks) afrag[ct][ks] = bf16x8{0,0,0,0,0,0,0,0};
        }
        // lanes {cr, cr+16, cr+32, cr+48} hold the 256 elements of row c
        ss += __shfl_xor(ss, 16);
        ss += __shfl_xor(ss, 32);
        const float rn = 1.0f / fmaxf(sqrtf(ss), 1e-12f);
        // lane j (<16) holds rn for class ct*16+j; epilogue lane needs classes
        // ct*16 + q*4 + r  ->  pull from lane q*4+r. (OOB classes: acc==0
        // exactly, so exp(0*srn)=1 regardless of huge srn -> OOB_COLS fix.)
#pragma unroll
        for (int r = 0; r < 4; ++r)
            srn[ct][r] = SCALE_F * __shfl(rn, q * 4 + r);
    }

    float* bout = banks + (size_t)(sl & (NBANK - 1)) * Bn;
    const bf16x8* bsrc = (const bf16x8*)embF;   // chunk-indexed (16B units)

    // B fragments for tile t: chunks t*512 + ks*64 + lane (coalesced 1KB/inst)
    auto load_b = [&](bf16x8* bf, int t) {
        const bf16x8* p = bsrc + (size_t)t * 512 + lane;
#pragma unroll
        for (int ks = 0; ks < 8; ++ks) bf[ks] = p[ks * 64];
    };

    auto compute = [&](const bf16x8* bf, int t) {
        f32x4 a0 = {0.f, 0.f, 0.f, 0.f};
        f32x4 a1 = {0.f, 0.f, 0.f, 0.f};
#pragma unroll
        for (int ks = 0; ks < 8; ++ks) {
            a0 = __builtin_amdgcn_mfma_f32_16x16x32_bf16(afrag[0][ks], bf[ks], a0, 0, 0, 0);
            a1 = __builtin_amdgcn_mfma_f32_16x16x32_bf16(afrag[1][ks], bf[ks], a1, 0, 0, 0);
        }
        // D layout: col=lane&15=sample, row=q*4+reg=class.
        float s = 0.0f;
#pragma unroll
        for (int r = 0; r < 4; ++r) {
            s += __expf(a0[r] * srn[0][r]);
            s += __expf(a1[r] * srn[1][r]);
        }
        s += __shfl_xor(s, 16);
        s += __shfl_xor(s, 32);
        if (lane < 16) atomicAdd(&bout[t * 16 + cr], s);
    };

    bf16x8 b0[8], b1[8];
    load_b(b0, 0);
    for (int t = 0; t < NT; t += 2) {
        load_b(b1, t + 1);                       // issue ~1 tile ahead of use
        compute(b0, t);
        load_b(b0, (t + 2) < NT ? (t + 2) : 0);  // overrun-clamped prefetch
        compute(b1, t + 1);
    }
}

// ---- kernel 3: fused bank-reduce + loss ----
// 32 blocks x 256 thr; block owns 64 samples; tid = qq*64 + l, qq = bank quarter.
__global__ __launch_bounds__(256) void k_finish(const float* __restrict__ banks,
                                                const float* __restrict__ numv,
                                                const float* __restrict__ etv,
                                                float* __restrict__ out) {
    __shared__ float red[64];
    const int l  = threadIdx.x & 63;
    const int qq = threadIdx.x >> 6;
    const int b  = blockIdx.x * 64 + l;

    if (threadIdx.x < 64) red[threadIdx.x] = 0.0f;
    __syncthreads();

    float acc = 0.0f;
#pragma unroll
    for (int k = 0; k < NBANK / 4; ++k)
        acc += banks[(size_t)(qq * (NBANK / 4) + k) * Bn + b];
    atomicAdd(&red[l], acc);
    __syncthreads();

    if (threadIdx.x < 64) {
        const float num  = numv[b];
        const float excl = red[l] - OOB_COLS - etv[b];   // drop padding + target col
        const float denom = __expf(num) + excl;
        float term = num - logf(denom + EPS_F);
#pragma unroll
        for (int o = 1; o < 64; o <<= 1) term += __shfl_xor(term, o);
        if (l == 0) atomicAdd(out, -term / (float)Bn);
    }
}

extern "C" void kernel_launch(void* const* d_in, const int* in_sizes, int n_in,
                              void* d_out, int out_size, void* d_ws, size_t ws_size,
                              hipStream_t stream) {
    const float* emb = (const float*)d_in[0];   // 2048*256
    const float* W   = (const float*)d_in[1];   // 100000*256
    const int*   tgt = (const int*)d_in[2];     // 2048
    float* out = (float*)d_out;

    char* ws = (char*)d_ws;
    short* embF  = (short*)ws;                              // 1 MB (fragment order)
    float* banks = (float*)(ws + (1 << 20));                // 64*2048*4 = 512 KB
    float* numv  = banks + (size_t)NBANK * Bn;              // 8 KB
    float* etv   = numv + Bn;                               // 8 KB

    hipMemsetAsync(out, 0, sizeof(float), stream);
    hipMemsetAsync(banks, 0, (size_t)NBANK * Bn * sizeof(float), stream);
    k_prep<<<768, 256, 0, stream>>>(W, emb, tgt, embF, numv, etv);
    k_main<<<NSLICE, 64, 0, stream>>>(W, embF, banks);
    k_finish<<<32, 256, 0, stream>>>(banks, numv, etv, out);
}